// Round 1
// baseline (1965.759 us; speedup 1.0000x reference)
//
#include <hip/hip_runtime.h>

// ---------------------------------------------------------------------------
// TransformerEncoder: B=4, S=2048, D=1024, H=16, HD=64, FF=4096
// Round 0: correctness-first bf16-MFMA decomposition.
//   cast -> GEMM(Q) GEMM(K) GEMM(V) -> attention -> GEMM(O) -> GEMM(FF1,relu)
//   -> GEMM(FF2, fp32 out)
// ---------------------------------------------------------------------------

typedef short bf16x8 __attribute__((ext_vector_type(8)));   // 8 bf16 bit patterns
typedef float f32x4 __attribute__((ext_vector_type(4)));

__device__ __forceinline__ unsigned short f2bf(float f) {
  unsigned int u = __builtin_bit_cast(unsigned int, f);
  u += 0x7fffu + ((u >> 16) & 1u);   // round-to-nearest-even
  return (unsigned short)(u >> 16);
}

// --------------------------- cast fp32 -> bf16 -----------------------------
__global__ __launch_bounds__(256) void cast_f32_bf16(
    const float* __restrict__ src, unsigned short* __restrict__ dst, int n4) {
  int i = blockIdx.x * 256 + threadIdx.x;
  if (i < n4) {
    float4 f = ((const float4*)src)[i];
    ushort4 o;
    o.x = f2bf(f.x); o.y = f2bf(f.y); o.z = f2bf(f.z); o.w = f2bf(f.w);
    ((ushort4*)dst)[i] = o;
  }
}

// ------------------------------- GEMM --------------------------------------
// C[M,N] = A[M,K] @ B[K,N] + bias[N]
// A,B bf16 row-major. EPI: 0 = fp32 out, 1 = bf16 out, 2 = bf16 out + relu.
// Block 256 thr (4 waves), tile 128x128, BK=32. Each wave owns 64x64.
// LDS row stride 40 (pad 8): 80B rows -> b128 aligned, ~2-way conflicts.
#define LDP 40

template <int EPI>
__global__ __launch_bounds__(256) void gemm_bf16(
    const unsigned short* __restrict__ A, const unsigned short* __restrict__ B,
    const float* __restrict__ bias, void* __restrict__ C,
    int M, int N, int K) {
  __shared__ unsigned short As[128 * LDP];
  __shared__ unsigned short Bs[128 * LDP];

  const int tid = threadIdx.x;
  const int wave = tid >> 6, lane = tid & 63;
  const int quad = lane >> 4, l16 = lane & 15;
  const int wm = (wave >> 1) * 64, wn = (wave & 1) * 64;
  const int m0 = blockIdx.y * 128, n0 = blockIdx.x * 128;

  // staging assignments
  const int sm = tid >> 1, skb = (tid & 1) * 16;    // A: row, k-offset
  const int sk = tid >> 3, snb = (tid & 7) * 16;    // B: k-row, n-offset

  f32x4 acc[4][4] = {};

  for (int k0 = 0; k0 < K; k0 += 32) {
    __syncthreads();
    // stage A tile [128][32] (row-major, contiguous in k)
    const int4* gA = (const int4*)(A + (size_t)(m0 + sm) * K + k0 + skb);
    *(int4*)(As + sm * LDP + skb) = gA[0];
    *(int4*)(As + sm * LDP + skb + 8) = gA[1];
    // stage B tile transposed -> Bs[n][k]
    const int4* gB = (const int4*)(B + (size_t)(k0 + sk) * N + n0 + snb);
    int4 b0 = gB[0], b1 = gB[1];
    const unsigned short* p0 = (const unsigned short*)&b0;
    const unsigned short* p1 = (const unsigned short*)&b1;
#pragma unroll
    for (int j = 0; j < 8; ++j) Bs[(snb + j) * LDP + sk] = p0[j];
#pragma unroll
    for (int j = 0; j < 8; ++j) Bs[(snb + 8 + j) * LDP + sk] = p1[j];
    __syncthreads();

    bf16x8 af[4], bfr[4];
#pragma unroll
    for (int mi = 0; mi < 4; ++mi)
      af[mi] = *(const bf16x8*)(As + (wm + mi * 16 + l16) * LDP + quad * 8);
#pragma unroll
    for (int ni = 0; ni < 4; ++ni)
      bfr[ni] = *(const bf16x8*)(Bs + (wn + ni * 16 + l16) * LDP + quad * 8);
#pragma unroll
    for (int mi = 0; mi < 4; ++mi)
#pragma unroll
      for (int ni = 0; ni < 4; ++ni)
        acc[mi][ni] = __builtin_amdgcn_mfma_f32_16x16x32_bf16(
            af[mi], bfr[ni], acc[mi][ni], 0, 0, 0);
  }

  // epilogue: C/D layout col=lane&15, row=quad*4+r
#pragma unroll
  for (int ni = 0; ni < 4; ++ni) {
    const int col = n0 + wn + ni * 16 + l16;
    const float bv = bias[col];
#pragma unroll
    for (int mi = 0; mi < 4; ++mi) {
      const int row = m0 + wm + mi * 16 + quad * 4;
#pragma unroll
      for (int r = 0; r < 4; ++r) {
        float v = acc[mi][ni][r] + bv;
        if (EPI == 2) v = v > 0.f ? v : 0.f;
        if (EPI == 0)
          ((float*)C)[(size_t)(row + r) * N + col] = v;
        else
          ((unsigned short*)C)[(size_t)(row + r) * N + col] = f2bf(v);
      }
    }
  }
}

// ----------------------------- attention -----------------------------------
// One block = one (b, h, 16-query tile). 256 thr = 4 waves.
// Phase 1: logits[16][2048] fp32 in LDS via QK^T MFMA (frags straight from
//          global: layout [lane&15][quad*8+j] matches row-major [S,D]).
// Phase 2: row softmax (16 threads/row, width-16 shuffles), P kept
//          unnormalized fp32 in LDS, 1/sum saved.
// Phase 3: ctx = P @ V via MFMA (a-frag: LDS fp32 -> bf16; b-frag: V gather),
//          scaled by 1/sum, written bf16.
__global__ __launch_bounds__(256) void attn_kernel(
    const unsigned short* __restrict__ Q, const unsigned short* __restrict__ K,
    const unsigned short* __restrict__ V, const int* __restrict__ lengths,
    unsigned short* __restrict__ ctx) {
  __shared__ float L[16 * 2052];   // pad 4 floats: 2-way banks, 16B-aligned rows
  __shared__ float sinv[16];
  const int S = 2048, D = 1024;

  const int bid = blockIdx.x;
  const int qt = bid & 127;
  const int h = (bid >> 7) & 15;
  const int b = bid >> 11;
  const int q0 = qt * 16;

  const int tid = threadIdx.x;
  const int wave = tid >> 6, lane = tid & 63;
  const int quad = lane >> 4, l16 = lane & 15;
  const int len = lengths[b];
  const size_t base = (size_t)b * S * D + (size_t)h * 64;

  // ---- phase 1: QK^T ----
  const unsigned short* qrow = Q + base + (size_t)(q0 + l16) * D;
  bf16x8 qf0 = *(const bf16x8*)(qrow + quad * 8);
  bf16x8 qf1 = *(const bf16x8*)(qrow + 32 + quad * 8);
  for (int kt = wave; kt < 128; kt += 4) {
    const int k0 = kt * 16;
    const unsigned short* krow = K + base + (size_t)(k0 + l16) * D;
    bf16x8 kf0 = *(const bf16x8*)(krow + quad * 8);
    bf16x8 kf1 = *(const bf16x8*)(krow + 32 + quad * 8);
    f32x4 c = {0.f, 0.f, 0.f, 0.f};
    c = __builtin_amdgcn_mfma_f32_16x16x32_bf16(qf0, kf0, c, 0, 0, 0);
    c = __builtin_amdgcn_mfma_f32_16x16x32_bf16(qf1, kf1, c, 0, 0, 0);
    const int col = k0 + l16;
    const bool masked = (col >= len);
#pragma unroll
    for (int r = 0; r < 4; ++r) {
      float v = c[r] * 0.125f;           // 1/sqrt(64)
      if (masked) v = -__builtin_inff();
      L[(quad * 4 + r) * 2052 + col] = v;
    }
  }
  __syncthreads();

  // ---- phase 2: softmax ----
  {
    const int row = tid >> 4, g = tid & 15;
    float* Lr = L + row * 2052;
    float m = -__builtin_inff();
    for (int c0 = g; c0 < 2048; c0 += 16) m = fmaxf(m, Lr[c0]);
#pragma unroll
    for (int off = 8; off > 0; off >>= 1) m = fmaxf(m, __shfl_xor(m, off, 16));
    float s = 0.f;
    for (int c0 = g; c0 < 2048; c0 += 16) {
      float p = __expf(Lr[c0] - m);      // exp(-inf)=0 for masked
      s += p;
      Lr[c0] = p;
    }
#pragma unroll
    for (int off = 8; off > 0; off >>= 1) s += __shfl_xor(s, off, 16);
    if (g == 0) sinv[row] = 1.0f / s;
  }
  __syncthreads();

  // ---- phase 3: P @ V ----
  {
    const int n0w = wave * 16;           // each wave: 16 of 64 head-dims
    const unsigned short* vcol = V + base + n0w + l16;
    f32x4 acc = {0.f, 0.f, 0.f, 0.f};
    for (int k0 = 0; k0 < 2048; k0 += 32) {
      const float* lp = L + l16 * 2052 + k0 + quad * 8;
      float4 fa0 = *(const float4*)lp;
      float4 fa1 = *(const float4*)(lp + 4);
      union { bf16x8 v; unsigned short u[8]; } av;
      av.u[0] = f2bf(fa0.x); av.u[1] = f2bf(fa0.y);
      av.u[2] = f2bf(fa0.z); av.u[3] = f2bf(fa0.w);
      av.u[4] = f2bf(fa1.x); av.u[5] = f2bf(fa1.y);
      av.u[6] = f2bf(fa1.z); av.u[7] = f2bf(fa1.w);
      union { bf16x8 v; unsigned short u[8]; } bv;
      const unsigned short* vp = vcol + (size_t)(k0 + quad * 8) * D;
#pragma unroll
      for (int j = 0; j < 8; ++j) bv.u[j] = vp[(size_t)j * D];
      acc = __builtin_amdgcn_mfma_f32_16x16x32_bf16(av.v, bv.v, acc, 0, 0, 0);
    }
#pragma unroll
    for (int r = 0; r < 4; ++r) {
      const int row = quad * 4 + r;
      float v = acc[r] * sinv[row];
      ctx[base + (size_t)(q0 + row) * D + n0w + l16] = f2bf(v);
    }
  }
}

// ------------------------------ launcher -----------------------------------
extern "C" void kernel_launch(void* const* d_in, const int* in_sizes, int n_in,
                              void* d_out, int out_size, void* d_ws,
                              size_t ws_size, hipStream_t stream) {
  const float* x  = (const float*)d_in[0];
  const int* lengths = (const int*)d_in[1];
  const float* qW = (const float*)d_in[2];
  const float* qb = (const float*)d_in[3];
  const float* kW = (const float*)d_in[4];
  const float* kb = (const float*)d_in[5];
  const float* vW = (const float*)d_in[6];
  const float* vb = (const float*)d_in[7];
  const float* oW = (const float*)d_in[8];
  const float* ob = (const float*)d_in[9];
  const float* w1 = (const float*)d_in[10];
  const float* b1 = (const float*)d_in[11];
  const float* w2 = (const float*)d_in[12];
  const float* b2 = (const float*)d_in[13];
  float* out = (float*)d_out;

  const int Bx = 4, S = 2048, D = 1024, H = 16, FF = 4096;
  const int M = Bx * S;  // 8192

  unsigned short* p = (unsigned short*)d_ws;
  unsigned short* xb  = p; p += (size_t)M * D;
  unsigned short* qWb = p; p += (size_t)D * D;
  unsigned short* kWb = p; p += (size_t)D * D;
  unsigned short* vWb = p; p += (size_t)D * D;
  unsigned short* oWb = p; p += (size_t)D * D;
  unsigned short* w1b = p; p += (size_t)D * FF;
  unsigned short* w2b = p; p += (size_t)FF * D;
  unsigned short* Qb  = p; p += (size_t)M * D;
  unsigned short* Kb  = p; p += (size_t)M * D;
  unsigned short* Vb  = p; p += (size_t)M * D;
  unsigned short* Cb  = p; p += (size_t)M * D;
  unsigned short* Ab  = p; p += (size_t)M * D;
  unsigned short* Hb  = p; p += (size_t)M * FF;

  auto cast = [&](const float* src, unsigned short* dst, size_t n) {
    int n4 = (int)(n / 4);
    cast_f32_bf16<<<dim3((n4 + 255) / 256), dim3(256), 0, stream>>>(src, dst, n4);
  };
  cast(x,  xb,  (size_t)M * D);
  cast(qW, qWb, (size_t)D * D);
  cast(kW, kWb, (size_t)D * D);
  cast(vW, vWb, (size_t)D * D);
  cast(oW, oWb, (size_t)D * D);
  cast(w1, w1b, (size_t)D * FF);
  cast(w2, w2b, (size_t)FF * D);

  dim3 blk(256);
  gemm_bf16<1><<<dim3(D / 128, M / 128), blk, 0, stream>>>(xb, qWb, qb, Qb, M, D, D);
  gemm_bf16<1><<<dim3(D / 128, M / 128), blk, 0, stream>>>(xb, kWb, kb, Kb, M, D, D);
  gemm_bf16<1><<<dim3(D / 128, M / 128), blk, 0, stream>>>(xb, vWb, vb, Vb, M, D, D);

  attn_kernel<<<dim3(Bx * H * (S / 16)), blk, 0, stream>>>(Qb, Kb, Vb, lengths, Cb);

  gemm_bf16<1><<<dim3(D / 128, M / 128), blk, 0, stream>>>(Cb, oWb, ob, Ab, M, D, D);
  gemm_bf16<2><<<dim3(FF / 128, M / 128), blk, 0, stream>>>(Ab, w1b, b1, Hb, M, FF, D);
  gemm_bf16<0><<<dim3(D / 128, M / 128), blk, 0, stream>>>(Hb, w2b, b2, out, M, D, FF);
}

// Round 2
// 589.337 us; speedup vs baseline: 3.3355x; 3.3355x over previous
//
#include <hip/hip_runtime.h>

// ---------------------------------------------------------------------------
// TransformerEncoder: B=4, S=2048, D=1024, H=16, HD=64, FF=4096
// Round 2: flash-attention (64q tile, online softmax, LDS-staged K/Vt) +
//          m97-style GEMMs (B^T weights, global_load_lds width-16 staging).
// ---------------------------------------------------------------------------

typedef short bf16x8 __attribute__((ext_vector_type(8)));
typedef float f32x4 __attribute__((ext_vector_type(4)));

__device__ __forceinline__ unsigned short f2bf(float f) {
  unsigned int u = __builtin_bit_cast(unsigned int, f);
  u += 0x7fffu + ((u >> 16) & 1u);   // round-to-nearest-even
  return (unsigned short)(u >> 16);
}

__device__ __forceinline__ void gload16(const unsigned short* g, unsigned short* l) {
  __builtin_amdgcn_global_load_lds(
      (const __attribute__((address_space(1))) unsigned int*)(g),
      (__attribute__((address_space(3))) unsigned int*)(l),
      16, 0, 0);
}

// --------------------------- cast fp32 -> bf16 -----------------------------
__global__ __launch_bounds__(256) void cast_f32_bf16(
    const float* __restrict__ src, unsigned short* __restrict__ dst, int n4) {
  int i = blockIdx.x * 256 + threadIdx.x;
  if (i < n4) {
    float4 f = ((const float4*)src)[i];
    ushort4 o;
    o.x = f2bf(f.x); o.y = f2bf(f.y); o.z = f2bf(f.z); o.w = f2bf(f.w);
    ((ushort4*)dst)[i] = o;
  }
}

// ------------------- cast + transpose: W[K,N] f32 -> Wt[N,K] bf16 ----------
// block 256 = 4 waves; wave w handles k-chunk of 8; lane = n offset.
// reads coalesced (256B/instr along N), writes 16B per lane (scattered).
__global__ __launch_bounds__(256) void cast_transpose(
    const float* __restrict__ W, unsigned short* __restrict__ Wt, int N, int K) {
  const int wave = threadIdx.x >> 6, lane = threadIdx.x & 63;
  const int n = blockIdx.x * 64 + lane;
  const int k0 = blockIdx.y * 32 + wave * 8;
  union { int4 v; unsigned short u[8]; } s;
#pragma unroll
  for (int j = 0; j < 8; ++j) s.u[j] = f2bf(W[(size_t)(k0 + j) * N + n]);
  *(int4*)(Wt + (size_t)n * K + k0) = s.v;
}

// ------------------------------- GEMM (B^T) --------------------------------
// C[M,N] = A[M,K] @ Bt[N,K]^T + bias[N]
// EPI: 0 fp32 out, 1 bf16 out, 2 bf16+relu, 3 bf16 scattered to Vt[b,h,dh,s].
// 256 thr / 4 waves, tile 128x128, BK=32, global_load_lds width-16 staging.
template <int EPI>
__global__ __launch_bounds__(256) void gemm_bt(
    const unsigned short* __restrict__ A, const unsigned short* __restrict__ Bt,
    const float* __restrict__ bias, void* __restrict__ C,
    int M, int N, int K) {
  __shared__ unsigned short As[128 * 32];
  __shared__ unsigned short Bs[128 * 32];

  const int tid = threadIdx.x;
  const int wave = tid >> 6, lane = tid & 63;
  const int quad = lane >> 4, l16 = lane & 15;
  const int wm = (wave >> 1) * 64, wn = (wave & 1) * 64;
  const int m0 = blockIdx.y * 128, n0 = blockIdx.x * 128;

  // staging: flat 16B unit u = c*256 + tid; row = u>>2, koff = (u&3)*8 elems
  const int u1 = tid, u2 = 256 + tid;
  const int r1 = u1 >> 2, c1 = (u1 & 3) * 8;
  const int r2 = u2 >> 2, c2 = (u2 & 3) * 8;
  const unsigned short* ga1 = A + (size_t)(m0 + r1) * K + c1;
  const unsigned short* ga2 = A + (size_t)(m0 + r2) * K + c2;
  const unsigned short* gb1 = Bt + (size_t)(n0 + r1) * K + c1;
  const unsigned short* gb2 = Bt + (size_t)(n0 + r2) * K + c2;
  unsigned short* lA1 = As + wave * 512;         // wave-uniform chunk bases
  unsigned short* lA2 = As + 2048 + wave * 512;
  unsigned short* lB1 = Bs + wave * 512;
  unsigned short* lB2 = Bs + 2048 + wave * 512;

  f32x4 acc[4][4] = {};

  for (int k0 = 0; k0 < K; k0 += 32) {
    __syncthreads();
    gload16(ga1 + k0, lA1);
    gload16(ga2 + k0, lA2);
    gload16(gb1 + k0, lB1);
    gload16(gb2 + k0, lB2);
    __syncthreads();

    bf16x8 af[4], bfr[4];
#pragma unroll
    for (int mi = 0; mi < 4; ++mi)
      af[mi] = *(const bf16x8*)(As + (wm + mi * 16 + l16) * 32 + quad * 8);
#pragma unroll
    for (int ni = 0; ni < 4; ++ni)
      bfr[ni] = *(const bf16x8*)(Bs + (wn + ni * 16 + l16) * 32 + quad * 8);
#pragma unroll
    for (int mi = 0; mi < 4; ++mi)
#pragma unroll
      for (int ni = 0; ni < 4; ++ni)
        acc[mi][ni] = __builtin_amdgcn_mfma_f32_16x16x32_bf16(
            af[mi], bfr[ni], acc[mi][ni], 0, 0, 0);
  }

#pragma unroll
  for (int ni = 0; ni < 4; ++ni) {
    const int col = n0 + wn + ni * 16 + l16;
    const float bv = bias[col];
#pragma unroll
    for (int mi = 0; mi < 4; ++mi) {
      const int row = m0 + wm + mi * 16 + quad * 4;
      if (EPI == 3) {
        // scatter to Vt[b, h, dh, s]: 4 consecutive s -> one 8B store
        const int bI = row >> 11, s = row & 2047;
        const int h = col >> 6, dh = col & 63;
        union { ushort4 v; unsigned short u[4]; } pk;
#pragma unroll
        for (int r = 0; r < 4; ++r) pk.u[r] = f2bf(acc[mi][ni][r] + bv);
        *(ushort4*)((unsigned short*)C +
                    ((size_t)((bI * 16 + h) * 64 + dh)) * 2048 + s) = pk.v;
      } else {
#pragma unroll
        for (int r = 0; r < 4; ++r) {
          float v = acc[mi][ni][r] + bv;
          if (EPI == 2) v = v > 0.f ? v : 0.f;
          if (EPI == 0)
            ((float*)C)[(size_t)(row + r) * N + col] = v;
          else
            ((unsigned short*)C)[(size_t)(row + r) * N + col] = f2bf(v);
        }
      }
    }
  }
}

// --------------------------- flash attention -------------------------------
// Block = (b, h, 64-query tile); 256 thr = 4 waves, wave owns 16 q-rows.
// K-tiles of 64 keys: Ks[64][72] (key-major), Vs = Vt tile [64 dh][72 s-pad].
// Online softmax (m,l per row, rescale O-acc). Early exit at ceil(len/64).
__global__ __launch_bounds__(256) void attn_fused(
    const unsigned short* __restrict__ Q, const unsigned short* __restrict__ K,
    const unsigned short* __restrict__ Vt, const int* __restrict__ lengths,
    unsigned short* __restrict__ ctx) {
  constexpr int S = 2048, D = 1024;
  __shared__ unsigned short Ks[64 * 72];
  __shared__ unsigned short Vs[64 * 72];
  __shared__ unsigned short Ps[4 * 16 * 72];

  const int tid = threadIdx.x;
  const int wave = tid >> 6, lane = tid & 63;
  const int quad = lane >> 4, l16 = lane & 15;
  const int bid = blockIdx.x;
  const int qt = bid & 31;
  const int h = (bid >> 5) & 15;
  const int b = bid >> 9;
  const int q0 = qt * 64;
  const int len = lengths[b];
  const int ktEnd = (len + 63) >> 6;
  const float NEGINF = -__builtin_inff();

  const size_t xbase = (size_t)b * S * D + (size_t)h * 64;

  // Q fragments (A-layout: m = l16 q-row, k = d), held in regs all kernel
  const unsigned short* qrow = Q + xbase + (size_t)(q0 + wave * 16 + l16) * D;
  const bf16x8 qf0 = *(const bf16x8*)(qrow + quad * 8);
  const bf16x8 qf1 = *(const bf16x8*)(qrow + 32 + quad * 8);

  // staging: unit u = c*256 + tid; row = u>>3, off = (u&7)*8 elems
  const int sr1 = tid >> 3, sc1 = (tid & 7) * 8;
  const int sr2 = (256 + tid) >> 3, sc2 = (tid & 7) * 8;
  const unsigned short* kg1 = K + xbase + (size_t)sr1 * D + sc1;
  const unsigned short* kg2 = K + xbase + (size_t)sr2 * D + sc2;
  const size_t vtb = (size_t)(b * 16 + h) * 64;
  const unsigned short* vg1 = Vt + (vtb + sr1) * S + sc1;
  const unsigned short* vg2 = Vt + (vtb + sr2) * S + sc2;

  f32x4 oacc[4] = {};
  float mprev[4], lsum[4];
#pragma unroll
  for (int r = 0; r < 4; ++r) { mprev[r] = NEGINF; lsum[r] = 0.f; }

  unsigned short* pw = Ps + wave * (16 * 72);

  for (int kt = 0; kt < ktEnd; ++kt) {
    const int k0 = kt * 64;
    __syncthreads();
    *(int4*)(Ks + sr1 * 72 + sc1) = *(const int4*)(kg1 + (size_t)k0 * D);
    *(int4*)(Ks + sr2 * 72 + sc2) = *(const int4*)(kg2 + (size_t)k0 * D);
    *(int4*)(Vs + sr1 * 72 + sc1) = *(const int4*)(vg1 + k0);
    *(int4*)(Vs + sr2 * 72 + sc2) = *(const int4*)(vg2 + k0);
    __syncthreads();

    // ---- QK^T: 4 col-blocks of 16 keys ----
    f32x4 sf[4];
#pragma unroll
    for (int cb = 0; cb < 4; ++cb) {
      const bf16x8 kf0 = *(const bf16x8*)(Ks + (cb * 16 + l16) * 72 + quad * 8);
      const bf16x8 kf1 = *(const bf16x8*)(Ks + (cb * 16 + l16) * 72 + 32 + quad * 8);
      f32x4 c = {0.f, 0.f, 0.f, 0.f};
      c = __builtin_amdgcn_mfma_f32_16x16x32_bf16(qf0, kf0, c, 0, 0, 0);
      c = __builtin_amdgcn_mfma_f32_16x16x32_bf16(qf1, kf1, c, 0, 0, 0);
      sf[cb] = c;
    }

    // ---- scale + mask + row max ----
    float mx[4] = {NEGINF, NEGINF, NEGINF, NEGINF};
#pragma unroll
    for (int cb = 0; cb < 4; ++cb) {
      const bool msk = (k0 + cb * 16 + l16) >= len;
#pragma unroll
      for (int r = 0; r < 4; ++r) {
        float v = sf[cb][r] * 0.125f;
        v = msk ? NEGINF : v;
        sf[cb][r] = v;
        mx[r] = fmaxf(mx[r], v);
      }
    }
#pragma unroll
    for (int off = 8; off > 0; off >>= 1)
#pragma unroll
      for (int r = 0; r < 4; ++r) mx[r] = fmaxf(mx[r], __shfl_xor(mx[r], off, 16));

    float alpha[4];
#pragma unroll
    for (int r = 0; r < 4; ++r) {
      const float mnew = fmaxf(mprev[r], mx[r]);
      alpha[r] = __expf(mprev[r] - mnew);   // first tile: exp(-inf)=0
      mprev[r] = mnew;
    }

    // ---- p = exp(s - m), row sum ----
    float rs[4] = {0.f, 0.f, 0.f, 0.f};
#pragma unroll
    for (int cb = 0; cb < 4; ++cb)
#pragma unroll
      for (int r = 0; r < 4; ++r) {
        const float p = __expf(sf[cb][r] - mprev[r]);
        sf[cb][r] = p;
        rs[r] += p;
      }
#pragma unroll
    for (int off = 8; off > 0; off >>= 1)
#pragma unroll
      for (int r = 0; r < 4; ++r) rs[r] += __shfl_xor(rs[r], off, 16);
#pragma unroll
    for (int r = 0; r < 4; ++r) lsum[r] = lsum[r] * alpha[r] + rs[r];

    // ---- P -> LDS (C-layout -> A-layout round trip), rescale O ----
#pragma unroll
    for (int cb = 0; cb < 4; ++cb)
#pragma unroll
      for (int r = 0; r < 4; ++r)
        pw[(quad * 4 + r) * 72 + cb * 16 + l16] = f2bf(sf[cb][r]);
#pragma unroll
    for (int cb = 0; cb < 4; ++cb)
#pragma unroll
      for (int r = 0; r < 4; ++r) oacc[cb][r] *= alpha[r];

    const bf16x8 pa0 = *(const bf16x8*)(pw + l16 * 72 + quad * 8);
    const bf16x8 pa1 = *(const bf16x8*)(pw + l16 * 72 + 32 + quad * 8);
#pragma unroll
    for (int cb = 0; cb < 4; ++cb) {
      const bf16x8 vb0 = *(const bf16x8*)(Vs + (cb * 16 + l16) * 72 + quad * 8);
      const bf16x8 vb1 = *(const bf16x8*)(Vs + (cb * 16 + l16) * 72 + 32 + quad * 8);
      oacc[cb] = __builtin_amdgcn_mfma_f32_16x16x32_bf16(pa0, vb0, oacc[cb], 0, 0, 0);
      oacc[cb] = __builtin_amdgcn_mfma_f32_16x16x32_bf16(pa1, vb1, oacc[cb], 0, 0, 0);
    }
  }

  // ---- epilogue: O / l ----
#pragma unroll
  for (int cb = 0; cb < 4; ++cb)
#pragma unroll
    for (int r = 0; r < 4; ++r) {
      const int row = q0 + wave * 16 + quad * 4 + r;
      const float v = oacc[cb][r] / lsum[r];
      ctx[xbase + (size_t)row * D + cb * 16 + l16] = f2bf(v);
    }
}

// ------------------------------ launcher -----------------------------------
extern "C" void kernel_launch(void* const* d_in, const int* in_sizes, int n_in,
                              void* d_out, int out_size, void* d_ws,
                              size_t ws_size, hipStream_t stream) {
  const float* x  = (const float*)d_in[0];
  const int* lengths = (const int*)d_in[1];
  const float* qW = (const float*)d_in[2];
  const float* qb = (const float*)d_in[3];
  const float* kW = (const float*)d_in[4];
  const float* kb = (const float*)d_in[5];
  const float* vW = (const float*)d_in[6];
  const float* vb = (const float*)d_in[7];
  const float* oW = (const float*)d_in[8];
  const float* ob = (const float*)d_in[9];
  const float* w1 = (const float*)d_in[10];
  const float* b1 = (const float*)d_in[11];
  const float* w2 = (const float*)d_in[12];
  const float* b2 = (const float*)d_in[13];
  float* out = (float*)d_out;

  const int Bx = 4, S = 2048, D = 1024, FF = 4096;
  const int M = Bx * S;  // 8192

  unsigned short* p = (unsigned short*)d_ws;
  unsigned short* xb  = p; p += (size_t)M * D;
  unsigned short* qWt = p; p += (size_t)D * D;
  unsigned short* kWt = p; p += (size_t)D * D;
  unsigned short* vWt = p; p += (size_t)D * D;
  unsigned short* oWt = p; p += (size_t)D * D;
  unsigned short* w1t = p; p += (size_t)D * FF;   // [FF, D]
  unsigned short* w2t = p; p += (size_t)FF * D;   // [D, FF]
  unsigned short* Qb  = p; p += (size_t)M * D;
  unsigned short* Kb  = p; p += (size_t)M * D;
  unsigned short* Vtb = p; p += (size_t)M * D;    // [B,H,64,S]
  unsigned short* Cb  = p; p += (size_t)M * D;
  unsigned short* Ab  = p; p += (size_t)M * D;
  unsigned short* Hb  = p; p += (size_t)M * FF;

  {
    int n4 = (int)((size_t)M * D / 4);
    cast_f32_bf16<<<dim3((n4 + 255) / 256), dim3(256), 0, stream>>>(x, xb, n4);
  }
  cast_transpose<<<dim3(D / 64, D / 32), dim3(256), 0, stream>>>(qW, qWt, D, D);
  cast_transpose<<<dim3(D / 64, D / 32), dim3(256), 0, stream>>>(kW, kWt, D, D);
  cast_transpose<<<dim3(D / 64, D / 32), dim3(256), 0, stream>>>(vW, vWt, D, D);
  cast_transpose<<<dim3(D / 64, D / 32), dim3(256), 0, stream>>>(oW, oWt, D, D);
  cast_transpose<<<dim3(FF / 64, D / 32), dim3(256), 0, stream>>>(w1, w1t, FF, D);
  cast_transpose<<<dim3(D / 64, FF / 32), dim3(256), 0, stream>>>(w2, w2t, D, FF);

  dim3 blk(256);
  gemm_bt<1><<<dim3(D / 128, M / 128), blk, 0, stream>>>(xb, qWt, qb, Qb, M, D, D);
  gemm_bt<1><<<dim3(D / 128, M / 128), blk, 0, stream>>>(xb, kWt, kb, Kb, M, D, D);
  gemm_bt<3><<<dim3(D / 128, M / 128), blk, 0, stream>>>(xb, vWt, vb, Vtb, M, D, D);

  attn_fused<<<dim3(Bx * 16 * (S / 64)), blk, 0, stream>>>(Qb, Kb, Vtb, lengths, Cb);

  gemm_bt<1><<<dim3(D / 128, M / 128), blk, 0, stream>>>(Cb, oWt, ob, Ab, M, D, D);
  gemm_bt<2><<<dim3(FF / 128, M / 128), blk, 0, stream>>>(Ab, w1t, b1, Hb, M, FF, D);
  gemm_bt<0><<<dim3(D / 128, M / 128), blk, 0, stream>>>(Hb, w2t, b2, out, M, D, FF);
}